// Round 1
// baseline (9161.370 us; speedup 1.0000x reference)
//
#include <hip/hip_runtime.h>
#include <hip/hip_bf16.h>
#include <math.h>

#define BB 512
#define HH 512
#define TT 1024

typedef __bf16 bf16;
typedef __bf16 bf16x8 __attribute__((ext_vector_type(8)));
typedef __bf16 bf16x4 __attribute__((ext_vector_type(4)));
typedef float f32x4 __attribute__((ext_vector_type(4)));

// ---------------- ws layout (bytes) ----------------
// Wt0  : [2048][512] bf16   @ 0        (2 MB)  = bf16(W_hh), row = gate-col, col = k
// WcT  : [2048][512] bf16   @ 2 MB     (2 MB)  = bf16(W_hh + W_fc ⊗ W_ih)
// bias0: [2048] f32         @ 4 MB     (8 KB)  = b_ih + b_hh
// biasC: [2048] f32         @ 4 MB+8K  (8 KB)  = bias0 + b_fc * W_ih
// hbuf0: [512][512] bf16    @ 4 MB+16K (512 KB)
// hbuf1: [512][512] bf16    @ +512 KB  (512 KB)
// cbuf : [512][512] f32     @ next     (1 MB)
#define WT0_OFF   0
#define WCT_OFF   2097152
#define B0_OFF    4194304
#define BC_OFF    4202496
#define H0_OFF    4210688
#define H1_OFF    4734976
#define C_OFF     5259264

__global__ void prep_weights(const float* __restrict__ Whh, const float* __restrict__ Wih,
                             const float* __restrict__ bih, const float* __restrict__ bhh,
                             const float* __restrict__ Wfc, const float* __restrict__ bfc,
                             bf16* __restrict__ Wt0, bf16* __restrict__ WcT,
                             float* __restrict__ bias0, float* __restrict__ biasC) {
    int col = blockIdx.x;                 // 0..2047 (gate-dim index)
    float wih = Wih[col];
    for (int k = threadIdx.x; k < HH; k += blockDim.x) {
        float w = Whh[col * HH + k];
        Wt0[col * HH + k] = (bf16)w;
        WcT[col * HH + k] = (bf16)(w + Wfc[k] * wih);
    }
    if (threadIdx.x == 0) {
        float b0 = bih[col] + bhh[col];
        bias0[col] = b0;
        biasC[col] = b0 + bfc[0] * wih;
    }
}

__global__ void prep_state(const float* __restrict__ h, const float* __restrict__ c,
                           bf16* __restrict__ h0buf, float* __restrict__ cbuf) {
    int i = blockIdx.x * blockDim.x + threadIdx.x;   // over B*H
    if (i < BB * HH) {
        h0buf[i] = (bf16)h[i];
        cbuf[i] = c[i];
    }
}

__device__ __forceinline__ float tanh_fast(float x) {
    float ax = fabsf(x);
    float e = __expf(-2.f * ax);
    float r = (1.f - e) / (1.f + e);
    return copysignf(r, x);
}
__device__ __forceinline__ float sigmoid_fast(float x) {
    return 1.f / (1.f + __expf(-x));
}

// One LSTM step (fused). grid = 256 (16 batch-tiles x 16 hidden-slices), block = 256 (4 waves).
// Wave w computes gate w: output tile [32 batch rows x 32 hidden cols].
// Also: hs==0 wg computes y[:, t-1] from the staged previous hidden state.
__global__ __launch_bounds__(256) void lstm_step(
    const bf16* __restrict__ Wt,      // [2048][512] bf16 (gate-col major)
    const float* __restrict__ bias,   // [2048]
    const bf16* __restrict__ hn_in,   // [512][512] bf16
    bf16* __restrict__ hn_out,        // [512][512] bf16
    float* __restrict__ cbuf,         // [512][512] f32
    const float* __restrict__ Wfc,    // [512] f32
    const float* __restrict__ bfc,    // [1]
    float* __restrict__ out,          // [512][1024] f32
    int t)
{
    __shared__ bf16 Alds[32 * 520];          // 32 rows, padded stride 520 (bank-safe)
    __shared__ float gLDS[4][32][32];        // i,f,g,o tiles

    const int tid  = threadIdx.x;
    const int wave = tid >> 6;
    const int lane = tid & 63;
    const int hs   = blockIdx.x & 15;
    const int bt   = blockIdx.x >> 4;

    // ---- stage previous hidden tile [32 x 512] into LDS ----
    {
        int row = tid >> 3;
        int cs  = (tid & 7) * 64;
        const bf16* src = hn_in + (size_t)(bt * 32 + row) * HH + cs;
        bf16* dst = Alds + row * 520 + cs;
        #pragma unroll
        for (int u = 0; u < 8; ++u)
            *(bf16x8*)(dst + u * 8) = *(const bf16x8*)(src + u * 8);
    }
    __syncthreads();

    // ---- FC output for the PREVIOUS step: y[b, t-1] = hn_in[b,:]·Wfc + bfc ----
    if (hs == 0 && t >= 1) {
        int row = tid >> 3, seg = tid & 7;
        float s = 0.f;
        const bf16* a = Alds + row * 520 + seg * 64;
        const float* w = Wfc + seg * 64;
        #pragma unroll
        for (int u = 0; u < 8; ++u) {
            bf16x8 v = *(const bf16x8*)(a + u * 8);
            #pragma unroll
            for (int e = 0; e < 8; ++e) s += (float)v[e] * w[u * 8 + e];
        }
        s += __shfl_xor(s, 1);
        s += __shfl_xor(s, 2);
        s += __shfl_xor(s, 4);
        if (seg == 0) out[(size_t)(bt * 32 + row) * TT + (t - 1)] = s + bfc[0];
    }

    // ---- MFMA: [32,512] @ [512,32] for this wave's gate ----
    f32x4 acc[2][2];
    #pragma unroll
    for (int i = 0; i < 2; ++i)
        #pragma unroll
        for (int j = 0; j < 2; ++j) acc[i][j] = (f32x4)0.f;

    const int l15  = lane & 15;
    const int kgrp = (lane >> 4) * 8;
    const bf16* bp0 = Wt + (size_t)(wave * HH + hs * 32 + l15) * HH + kgrp;
    const bf16* bp1 = bp0 + 16 * HH;
    const bf16* ap0 = Alds + l15 * 520 + kgrp;
    const bf16* ap1 = ap0 + 16 * 520;

    #pragma unroll
    for (int kk = 0; kk < 16; ++kk) {
        bf16x8 a0 = *(const bf16x8*)(ap0 + kk * 32);
        bf16x8 a1 = *(const bf16x8*)(ap1 + kk * 32);
        bf16x8 b0 = *(const bf16x8*)(bp0 + kk * 32);
        bf16x8 b1 = *(const bf16x8*)(bp1 + kk * 32);
        acc[0][0] = __builtin_amdgcn_mfma_f32_16x16x32_bf16(a0, b0, acc[0][0], 0, 0, 0);
        acc[0][1] = __builtin_amdgcn_mfma_f32_16x16x32_bf16(a0, b1, acc[0][1], 0, 0, 0);
        acc[1][0] = __builtin_amdgcn_mfma_f32_16x16x32_bf16(a1, b0, acc[1][0], 0, 0, 0);
        acc[1][1] = __builtin_amdgcn_mfma_f32_16x16x32_bf16(a1, b1, acc[1][1], 0, 0, 0);
    }

    // ---- write gate tile (+bias) to LDS ----
    const int r4 = (lane >> 4) * 4;
    #pragma unroll
    for (int nt = 0; nt < 2; ++nt) {
        float bv = bias[wave * HH + hs * 32 + nt * 16 + l15];
        #pragma unroll
        for (int mt = 0; mt < 2; ++mt)
            #pragma unroll
            for (int r = 0; r < 4; ++r)
                gLDS[wave][mt * 16 + r4 + r][nt * 16 + l15] = acc[mt][nt][r] + bv;
    }
    __syncthreads();

    // ---- pointwise LSTM cell update (each thread: 1 row x 4 cols) ----
    {
        int bl = tid >> 3;
        int j0 = (tid & 7) * 4;
        int gB = bt * 32 + bl;
        int gJ = hs * 32 + j0;
        size_t base = (size_t)gB * HH + gJ;
        float4 cold = *(const float4*)&cbuf[base];
        float cn[4], hn[4];
        #pragma unroll
        for (int u = 0; u < 4; ++u) {
            float xi = gLDS[0][bl][j0 + u];
            float xf = gLDS[1][bl][j0 + u];
            float xg = gLDS[2][bl][j0 + u];
            float xo = gLDS[3][bl][j0 + u];
            float si = sigmoid_fast(xi);
            float sf = sigmoid_fast(xf);
            float so = sigmoid_fast(xo);
            float tg = tanh_fast(xg);
            float cv = (u == 0) ? cold.x : (u == 1) ? cold.y : (u == 2) ? cold.z : cold.w;
            float c2 = sf * cv + si * tg;
            cn[u] = c2;
            hn[u] = so * tanh_fast(c2);
        }
        *(float4*)&cbuf[base] = make_float4(cn[0], cn[1], cn[2], cn[3]);
        bf16x4 hv;
        #pragma unroll
        for (int u = 0; u < 4; ++u) hv[u] = (bf16)hn[u];
        *(bf16x4*)&hn_out[base] = hv;
    }
}

extern "C" void kernel_launch(void* const* d_in, const int* in_sizes, int n_in,
                              void* d_out, int out_size, void* d_ws, size_t ws_size,
                              hipStream_t stream) {
    const float* h   = (const float*)d_in[0];
    const float* c   = (const float*)d_in[1];
    const float* Wih = (const float*)d_in[2];
    const float* Whh = (const float*)d_in[3];
    const float* bih = (const float*)d_in[4];
    const float* bhh = (const float*)d_in[5];
    const float* Wfc = (const float*)d_in[6];
    const float* bfc = (const float*)d_in[7];
    float* out = (float*)d_out;

    char* ws = (char*)d_ws;
    bf16*  Wt0   = (bf16*)(ws + WT0_OFF);
    bf16*  WcT   = (bf16*)(ws + WCT_OFF);
    float* bias0 = (float*)(ws + B0_OFF);
    float* biasC = (float*)(ws + BC_OFF);
    bf16*  hb0   = (bf16*)(ws + H0_OFF);
    bf16*  hb1   = (bf16*)(ws + H1_OFF);
    float* cbuf  = (float*)(ws + C_OFF);

    prep_weights<<<2048, 256, 0, stream>>>(Whh, Wih, bih, bhh, Wfc, bfc, Wt0, WcT, bias0, biasC);
    prep_state<<<1024, 256, 0, stream>>>(h, c, hb0, cbuf);

    bf16* bufs[2] = { hb0, hb1 };
    for (int t = 0; t <= TT; ++t) {
        const bf16* Wt = (t == 0) ? Wt0 : WcT;
        const float* bias = (t == 0) ? bias0 : biasC;
        lstm_step<<<256, 256, 0, stream>>>(Wt, bias, bufs[t & 1], bufs[(t + 1) & 1],
                                           cbuf, Wfc, bfc, out, t);
    }
}